// Round 7
// baseline (114.994 us; speedup 1.0000x reference)
//
#include <hip/hip_runtime.h>
#include <math.h>

#define NSAMP 32768
#define FS_F 44100.0f
#define PI_F 3.14159265358979323846f
#define T1 1024  // KS slice length (32 slices/batch)
#define FLAG_MAGIC 0x5A5A5A5A

// LDS layout (floats, dynamic):
//   xall [0, 33792)      whole-span preLP'd excitation (32768 + 1024 pad)
//   prog [33792]         scan progress counter (int, 16-float slot)
//   tabs [33808, 40720)  body tables (bandc/Qlev/Qw/Rtab)
// body overlays: sl = [0,5376), body lws/lc0/lc1 at [6144..6248)
#define XALL_FLOATS 33792
#define PROG_OFF 33792
#define TABS_OFF 33808
#define SMEM_FLOATS 40720  // 162880 bytes (<= 163840)

struct BParams {
  float alpha, alpha_p;
  float fr, g, s;
  int Di;
  float lc, lm, lp;
};

__device__ inline float sigmoidf_(float x) { return 1.0f / (1.0f + expf(-x)); }

__device__ inline BParams compute_params(int b, const float* __restrict__ pitch,
                                         const float* __restrict__ w1,
                                         const float* __restrict__ b1,
                                         const float* __restrict__ w2,
                                         const float* __restrict__ b2) {
  BParams P;
  float p = pitch[b];
  float h[16];
#pragma unroll
  for (int i = 0; i < 16; ++i) {
    float v = fmaf(p, w1[i], b1[i]);
    h[i] = v > 0.0f ? v : 0.0f;
  }
  float m[3];
#pragma unroll
  for (int j = 0; j < 3; ++j) {
    float acc = b2[j];
#pragma unroll
    for (int i = 0; i < 16; ++i) acc = fmaf(h[i], w2[j * 16 + i], acc);
    m[j] = acc;
  }
  P.lc = fminf(fmaxf(m[0], -2.0f), 2.5f);
  P.lm = fminf(fmaxf(m[1], -2.5f), 0.0f);
  P.lp = fminf(fmaxf(m[2], -4.0f), 4.0f);
  P.g = 0.999f * sigmoidf_(P.lc);
  P.s = sigmoidf_(P.lm);
  float f0 = fmaxf(p, 60.0f);
  float D = fminf(fmaxf(FS_F / f0, 2.0f), 735.0f);
  int Di = (int)floorf(D);
  P.fr = D - (float)Di;
  P.Di = Di;
  float mult = fminf(fmaxf(2.0f + 6.0f * (f0 - 60.0f) / 600.0f, 2.0f), 8.0f);
  float cutoff = fminf(2.0f * PI_F * f0 * mult / FS_F, PI_F * 0.9f);
  P.alpha = 1.0f - expf(-cutoff);
  float cpost = fminf(PI_F * sigmoidf_(P.lp), PI_F * 0.99f);
  P.alpha_p = 1.0f - expf(-cpost);
  return P;
}

// lane helpers (wave64)
__device__ inline float rlv(float v, int l) {
  return __int_as_float(__builtin_amdgcn_readlane(__float_as_int(v), l));
}
__device__ inline float shr1(float v, float bnd) {
  return __int_as_float(__builtin_amdgcn_update_dpp(
      __float_as_int(bnd), __float_as_int(v), 0x138 /*wave_shr:1*/, 0xf, 0xf,
      false));
}
// rotate right by 1: lane0 <- lane63
__device__ inline float ror1(float v) {
  return __int_as_float(__builtin_amdgcn_update_dpp(
      __float_as_int(v), __float_as_int(v), 0x13C /*wave_ror:1*/, 0xf, 0xf,
      false));
}

__device__ inline void band_coef(int k, float& a1, float& a2, float& b0) {
  float fc = 80.0f * exp2f((float)k * (6.64385618977472436f / 23.0f));
  float w = 2.0f * PI_F * fc / FS_F;
  float r = expf(-PI_F * fc / (10.0f * FS_F));
  a1 = -2.0f * r * cosf(w);
  a2 = r * r;
  b0 = 1.0f - r;
}

// ---- data-independent body tables (verified bit-exact vs in-body compute) --
__device__ inline void gen_tables(float* __restrict__ tabs, int W) {
  if (W >= 120) return;
  const int j = W / 5, sub = W % 5;
  float A1, A2, B0;
  band_coef(j, A1, A2, B0);
  if (sub == 0) *(float4*)&tabs[j * 4] = make_float4(A1, A2, B0, 0.f);
  float Q00 = -A1, Q01 = -A2, Q10 = 1.f, Q11 = 0.f;
#pragma unroll
  for (int sq = 0; sq < 2; ++sq) {
    float n00 = fmaf(Q00, Q00, Q01 * Q10);
    float n01 = fmaf(Q00, Q01, Q01 * Q11);
    float n10 = fmaf(Q10, Q00, Q11 * Q10);
    float n11 = fmaf(Q10, Q01, Q11 * Q11);
    Q00 = n00; Q01 = n01; Q10 = n10; Q11 = n11;
  }
  float K00 = Q00, K01 = Q01, K10 = Q10, K11 = Q11;
#pragma unroll
  for (int sq = 0; sq < 2; ++sq) {
    float n00 = fmaf(Q00, Q00, Q01 * Q10);
    float n01 = fmaf(Q00, Q01, Q01 * Q11);
    float n10 = fmaf(Q10, Q00, Q11 * Q10);
    float n11 = fmaf(Q10, Q01, Q11 * Q11);
    Q00 = n00; Q01 = n01; Q10 = n10; Q11 = n11;
  }
  float L00[7], L01[7], L10[7], L11[7];
  L00[0] = fmaf(Q00, K00, Q01 * K10);
  L01[0] = fmaf(Q00, K01, Q01 * K11);
  L10[0] = fmaf(Q10, K00, Q11 * K10);
  L11[0] = fmaf(Q10, K01, Q11 * K11);
#pragma unroll
  for (int k = 0; k < 6; ++k) {
    float s00 = fmaf(L00[k], L00[k], L01[k] * L10[k]);
    float s01 = fmaf(L00[k], L01[k], L01[k] * L11[k]);
    float s10 = fmaf(L10[k], L00[k], L11[k] * L10[k]);
    float s11 = fmaf(L10[k], L01[k], L11[k] * L11[k]);
    L00[k + 1] = s00; L01[k + 1] = s01; L10[k + 1] = s10; L11[k + 1] = s11;
  }
  if (sub == 0) {
#pragma unroll
    for (int k = 0; k < 6; ++k)
      *(float4*)&tabs[96 + (k * 24 + j) * 4] =
          make_float4(L00[k], L01[k], L10[k], L11[k]);
    *(float4*)&tabs[672 + j * 4] = make_float4(L00[6], L01[6], L10[6], L11[6]);
  }
  int l0 = sub * 13, l1 = l0 + 13;
  if (l1 > 64) l1 = 64;
  for (int l = l0; l < l1; ++l) {
    float R00 = 1.f, R01 = 0.f, R10 = 0.f, R11 = 1.f;
#pragma unroll
    for (int bit = 0; bit < 6; ++bit) {
      if ((l >> bit) & 1) {
        float n00 = fmaf(L00[bit], R00, L01[bit] * R10);
        float n01 = fmaf(L00[bit], R01, L01[bit] * R11);
        float n10 = fmaf(L10[bit], R00, L11[bit] * R10);
        float n11 = fmaf(L10[bit], R01, L11[bit] * R11);
        R00 = n00; R01 = n01; R10 = n10; R11 = n11;
      }
    }
    *(float4*)&tabs[768 + (j * 64 + l) * 4] = make_float4(R00, R01, R10, R11);
  }
}

// wave1: register prefetch of one segment (32 samples/lane), guarded
__device__ inline void w1_load(const float* __restrict__ xg, int s1, int seg,
                               int lane, float4* pf) {
  const int base = s1 + (seg << 11) + (lane << 5);
#pragma unroll
  for (int i = 0; i < 8; ++i) {
    const int g = base + 4 * i;
    float4 v = make_float4(0.f, 0.f, 0.f, 0.f);
    if (g >= 0 && g + 3 < NSAMP) v = *(const float4*)&xg[g];
    pf[i] = v;
  }
}

// One KS period step. FP op sequence identical to R2..R6 (bit-identical).
// STORES is a compile-time flag (dead-code eliminated in warm-up copies).
#define KS_STEP(STORES)                                                       \
  do {                                                                        \
    float b2v[KNUM], b3v[KNUM];                                               \
    b2v[0] = shr1(yp[0], p1);                                                 \
    _Pragma("unroll") for (int k = 1; k < KNUM; ++k)                          \
        b2v[k] = shr1(yp[k], ror1(yp[k - 1]));                                \
    b3v[0] = shr1(b2v[0], p2);                                                \
    _Pragma("unroll") for (int k = 1; k < KNUM; ++k)                          \
        b3v[k] = shr1(b2v[k], ror1(b2v[k - 1]));                              \
    float p1n = rlv(yp[KNUM - 1], lq1);                                       \
    float p2n = rlv(b2v[KNUM - 1], lq1);                                      \
    _Pragma("unroll") for (int k = 0; k < KNUM; ++k)                          \
        yp[k] =                                                               \
            fmaf(c0w, yp[k], fmaf(c2w, b3v[k], fmaf(c1w, b2v[k], xC[k])));    \
    p1 = p1n;                                                                 \
    p2 = p2n;                                                                 \
    if (STORES) {                                                             \
      _Pragma("unroll") for (int k = 0; k < KNUM; ++k) {                      \
        int i = lane + (k << 6);                                              \
        int n = s1 + rel + i;                                                 \
        bool okl = (k < KNUM - 1) || (lane <= lq1);                           \
        if (okl && n >= n0 && n < end) yg[n] = yp[k];                         \
      }                                                                       \
    }                                                                         \
    int r2 = rel + 2 * C;                                                     \
    if (r2 < span) {                                                          \
      const float* xp = &xall[r2 + lane];                                     \
      _Pragma("unroll") for (int k = 0; k < KNUM; ++k) {                      \
        xC[k] = xN[k];                                                        \
        xN[k] = xp[k << 6];                                                   \
      }                                                                       \
    } else {                                                                  \
      _Pragma("unroll") for (int k = 0; k < KNUM; ++k) xC[k] = xN[k];         \
    }                                                                         \
    rel += C;                                                                 \
  } while (0)

// ---- single-wave KS recurrence (wave 0): flat LDS input, no block barriers.
// Period loop hand-unrolled 4x (runtime trip count -> compiler won't unroll):
// amortizes branch/waitcnt/hazard overhead and lets the scheduler overlap
// step j's LDS reads & global stores with step j+1's DPP/FMA chain.
template <int KNUM>
__device__ void ks_wave0(float* __restrict__ yg, const float* xall,
                         int* __restrict__ prog, int lane, int C, float c0w,
                         float c1w, float c2w, int s1, int n0, int end,
                         int span, int NSG) {
  const int lq1 = (C - 1) - (KNUM - 1) * 64;
  const int W = n0 - s1;
  float yp[KNUM], xC[KNUM], xN[KNUM];
  float p1 = 0.f, p2 = 0.f;
  int rel = 0;
#pragma unroll
  for (int k = 0; k < KNUM; ++k) { yp[k] = 0.f; xC[k] = 0.f; xN[k] = 0.f; }
  for (int s = 0; s < NSG; ++s) {
    int need = s + 3;
    if (need > NSG) need = NSG;
    while (__hip_atomic_load(prog, __ATOMIC_ACQUIRE,
                             __HIP_MEMORY_SCOPE_WORKGROUP) < need) {
      __builtin_amdgcn_s_sleep(1);
    }
    if (s == 0) {
#pragma unroll
      for (int k = 0; k < KNUM; ++k) {
        int i = lane + (k << 6);
        xC[k] = xall[i];
        xN[k] = xall[C + i];
      }
    }
    int fence = (s + 1) << 11;
    if (fence > span) fence = span;
    // lean warm-up (no stores): 4x unrolled + remainder
    while (rel + 4 * C <= W && rel + 3 * C < fence) {
      KS_STEP(false); KS_STEP(false); KS_STEP(false); KS_STEP(false);
    }
    while (rel + C <= W && rel < fence) KS_STEP(false);
    // live region (stores): 4x unrolled + remainder
    while (rel + 3 * C < fence) {
      KS_STEP(true); KS_STEP(true); KS_STEP(true); KS_STEP(true);
    }
    while (rel < fence) KS_STEP(true);
  }
}

// ---- KS phase: wave1 free-runs the preLP scan into flat xall, publishing a
// progress flag per segment (atomic-release drains the ds_writes). wave0
// free-runs the KS recurrence, polling the flag (acquire). waves 2-3 generate
// the body tables. NO block barriers inside the phase. ----
__device__ inline void ks_phase(int b, int q, const BParams& P,
                                const float* __restrict__ exc, float scale0,
                                float* __restrict__ buf1, float* xall,
                                int* prog, float* tabs, int t) {
  const int C = P.Di;
  const int n0 = q << 10;
  float lg = -logf(P.g);
  int Wp = (int)ceilf(10.5f / fmaxf(lg, 1e-6f));
  if (Wp > 64) Wp = 64;
  if (Wp < 4) Wp = 4;
  int W = Wp * C;
  if (W > n0) W = n0;
  W = (W + 3) & ~3;
  const int s1 = n0 - W;
  const int span = W + T1;
  const int end = n0 + T1;
  const int NSG = (span + 2047) >> 11;  // segments covering span, <= 16
  float* yg = buf1 + (size_t)b * NSAMP;
  const float* xg = exc + (size_t)b * NSAMP;

  const float c = 1.0f - P.alpha;
  const float scale = scale0 * P.alpha;
  const int lane = t & 63, wid = t >> 6;

  // init: progress flag + zero the pad region [NSG*2048, +1024)
  if (t == 0) *prog = 0;
  *(float4*)&xall[(NSG << 11) + 4 * t] = make_float4(0.f, 0.f, 0.f, 0.f);
  __syncthreads();

  const float c0w = P.g * (1.0f - P.s) * (1.0f - P.fr);
  const float c1w = P.g * ((1.0f - P.s) * P.fr + P.s * (1.0f - P.fr));
  const float c2w = P.g * P.s * P.fr;

  if (wid == 0) {
    switch ((C + 63) >> 6) {
      case 2:  ks_wave0<2>(yg, xall, prog, lane, C, c0w, c1w, c2w, s1, n0, end, span, NSG); break;
      case 3:  ks_wave0<3>(yg, xall, prog, lane, C, c0w, c1w, c2w, s1, n0, end, span, NSG); break;
      case 4:  ks_wave0<4>(yg, xall, prog, lane, C, c0w, c1w, c2w, s1, n0, end, span, NSG); break;
      case 5:  ks_wave0<5>(yg, xall, prog, lane, C, c0w, c1w, c2w, s1, n0, end, span, NSG); break;
      case 6:  ks_wave0<6>(yg, xall, prog, lane, C, c0w, c1w, c2w, s1, n0, end, span, NSG); break;
      case 7:  ks_wave0<7>(yg, xall, prog, lane, C, c0w, c1w, c2w, s1, n0, end, span, NSG); break;
      case 8:  ks_wave0<8>(yg, xall, prog, lane, C, c0w, c1w, c2w, s1, n0, end, span, NSG); break;
      case 9:  ks_wave0<9>(yg, xall, prog, lane, C, c0w, c1w, c2w, s1, n0, end, span, NSG); break;
      case 10: ks_wave0<10>(yg, xall, prog, lane, C, c0w, c1w, c2w, s1, n0, end, span, NSG); break;
      case 11: ks_wave0<11>(yg, xall, prog, lane, C, c0w, c1w, c2w, s1, n0, end, span, NSG); break;
      default: ks_wave0<12>(yg, xall, prog, lane, C, c0w, c1w, c2w, s1, n0, end, span, NSG); break;
    }
  } else if (wid == 1) {
    // producer: scan segments -1 (vrun pre-warm, no write) .. NSG-1
    float c2v = c * c, c4 = c2v * c2v, c8 = c4 * c4;
    float m1 = c8, m2 = m1 * m1, m4 = m2 * m2, m8 = m4 * m4, m16 = m8 * m8,
          m32 = m16 * m16;
    float c512 = m32 * m32;
    float c1024 = c512 * c512;
    float c2048 = c1024 * c1024;
    const float n1 = m4, n2 = m8, n4 = m16, n8 = m32, n16 = c512,
                n32 = c512 * c512;
    const float c32lane = exp2f((float)(lane << 5) * log2f(c));
    float vrun = 0.0f;
    float4 pf[8], pg[8];
    w1_load(xg, s1, -1, lane, pf);
    w1_load(xg, s1, 0, lane, pg);
    for (int ls = -1; ls < NSG; ++ls) {
      float S = 0.0f;
#pragma unroll
      for (int i = 0; i < 8; ++i) {
        S = fmaf(c, S, scale * pf[i].x);
        S = fmaf(c, S, scale * pf[i].y);
        S = fmaf(c, S, scale * pf[i].z);
        S = fmaf(c, S, scale * pf[i].w);
      }
      float Sw = S, u;
      u = __shfl_up(Sw, 1);  if (lane >= 1)  Sw = fmaf(n1, u, Sw);
      u = __shfl_up(Sw, 2);  if (lane >= 2)  Sw = fmaf(n2, u, Sw);
      u = __shfl_up(Sw, 4);  if (lane >= 4)  Sw = fmaf(n4, u, Sw);
      u = __shfl_up(Sw, 8);  if (lane >= 8)  Sw = fmaf(n8, u, Sw);
      u = __shfl_up(Sw, 16); if (lane >= 16) Sw = fmaf(n16, u, Sw);
      u = __shfl_up(Sw, 32); if (lane >= 32) Sw = fmaf(n32, u, Sw);
      float tot = rlv(Sw, 63);
      float Sex = __shfl_up(Sw, 1);
      if (lane == 0) Sex = 0.0f;
      if (ls >= 0) {
        float v = fmaf(c32lane, vrun, Sex);
        const int o = (ls << 11) + (lane << 5);
#pragma unroll
        for (int i = 0; i < 8; ++i) {
          float4 y;
          v = fmaf(c, v, scale * pf[i].x); y.x = v;
          v = fmaf(c, v, scale * pf[i].y); y.y = v;
          v = fmaf(c, v, scale * pf[i].z); y.z = v;
          v = fmaf(c, v, scale * pf[i].w); y.w = v;
          *(float4*)&xall[o + 4 * i] = y;
        }
      }
      vrun = fmaf(c2048, vrun, tot);
      if (ls >= 0 && lane == 0) {
        // release: drains the ds_writes above before publishing
        __hip_atomic_store(prog, ls + 1, __ATOMIC_RELEASE,
                           __HIP_MEMORY_SCOPE_WORKGROUP);
      }
#pragma unroll
      for (int i = 0; i < 8; ++i) pf[i] = pg[i];
      if (ls + 2 < NSG) w1_load(xg, s1, ls + 2, lane, pg);
    }
  } else {
    gen_tables(tabs, (wid - 2) * 64 + lane);
  }
}

// One-pole scan over [s2, s2+nt*2048) from global into LDS sl[n-s2], reads
// clamped at `lim`.
__device__ inline void lpc_lds(const float* __restrict__ xg,
                               float* __restrict__ sl, int s2, int nt, int lim,
                               float scale, float c, int t, float* lws) {
  const int lane = t & 63, wid = t >> 6;
  float c2v = c * c, c4 = c2v * c2v, c8 = c4 * c4;
  float m1 = c8, m2 = m1 * m1, m4 = m2 * m2, m8 = m4 * m4, m16 = m8 * m8,
        m32 = m16 * m16;
  float c512 = m32 * m32;
  float c2048 = c512 * c512;
  c2048 *= c2048;
  float l2c = log2f(c);
  float c8lane = exp2f((float)(8 * lane) * l2c);
  float cgk = exp2f((float)(8 * t) * l2c);
  float vrun = 0.0f;
  for (int tile = 0; tile < nt; ++tile) {
    __syncthreads();
    int g0 = s2 + (tile << 11) + 8 * t;
    float4 xa = make_float4(0.f, 0.f, 0.f, 0.f);
    float4 xb = make_float4(0.f, 0.f, 0.f, 0.f);
    if (g0 + 3 < lim) xa = *(const float4*)&xg[g0];
    if (g0 + 7 < lim) xb = *(const float4*)&xg[g0 + 4];
    float S = 0.0f;
    S = fmaf(c, S, scale * xa.x); S = fmaf(c, S, scale * xa.y);
    S = fmaf(c, S, scale * xa.z); S = fmaf(c, S, scale * xa.w);
    S = fmaf(c, S, scale * xb.x); S = fmaf(c, S, scale * xb.y);
    S = fmaf(c, S, scale * xb.z); S = fmaf(c, S, scale * xb.w);
    float Sw = S, u;
    u = __shfl_up(Sw, 1);  if (lane >= 1)  Sw = fmaf(m1, u, Sw);
    u = __shfl_up(Sw, 2);  if (lane >= 2)  Sw = fmaf(m2, u, Sw);
    u = __shfl_up(Sw, 4);  if (lane >= 4)  Sw = fmaf(m4, u, Sw);
    u = __shfl_up(Sw, 8);  if (lane >= 8)  Sw = fmaf(m8, u, Sw);
    u = __shfl_up(Sw, 16); if (lane >= 16) Sw = fmaf(m16, u, Sw);
    u = __shfl_up(Sw, 32); if (lane >= 32) Sw = fmaf(m32, u, Sw);
    if (lane == 63) lws[wid] = Sw;
    __syncthreads();
    float a0 = lws[0], a1w = lws[1], a2w = lws[2], a3w = lws[3];
    float carry = (wid == 1)   ? a0
                  : (wid == 2) ? fmaf(c512, a0, a1w)
                  : (wid == 3) ? fmaf(c512, fmaf(c512, a0, a1w), a2w)
                               : 0.0f;
    float Sprev = __shfl_up(Sw, 1);
    float Sex = (lane == 0) ? 0.0f : Sprev;
    Sex = fmaf(c8lane, carry, Sex);
    float v = fmaf(cgk, vrun, Sex);
    int o = g0 - s2;
    float4 ya, yb;
    v = fmaf(c, v, scale * xa.x); ya.x = v;
    v = fmaf(c, v, scale * xa.y); ya.y = v;
    v = fmaf(c, v, scale * xa.z); ya.z = v;
    v = fmaf(c, v, scale * xa.w); ya.w = v;
    v = fmaf(c, v, scale * xb.x); yb.x = v;
    v = fmaf(c, v, scale * xb.y); yb.y = v;
    v = fmaf(c, v, scale * xb.z); yb.z = v;
    v = fmaf(c, v, scale * xb.w); yb.w = v;
    *(float4*)&sl[o] = ya;
    *(float4*)&sl[o + 4] = yb;
    float tS = fmaf(c512, fmaf(c512, fmaf(c512, a0, a1w), a2w), a3w);
    vrun = fmaf(c2048, vrun, tS);
  }
}

// ---- body phase, T2=1024; matrix powers loaded from LDS tables ----
__device__ inline void body_phase(int b, int q, const BParams& P,
                                  const float* __restrict__ gains,
                                  const float* __restrict__ buf1,
                                  float* __restrict__ out, float* sl,
                                  float* lws, float (*lc0)[8],
                                  float (*lc1)[8], const float* tabs, int t) {
  const int lane = t & 63, wid = t >> 6;
  const int n0 = q << 10;
  const int base = n0 - 4096;
  int s2 = base - 256;
  if (s2 < 0) s2 = 0;
  const int end = n0 + 1024;
  const int nt = (end - s2 + 2047) >> 11;  // <= 3

  lpc_lds(buf1 + (size_t)b * NSAMP, sl, s2, nt, end, P.alpha_p,
          1.0f - P.alpha_p, t, lws);
  __syncthreads();

  const float* bandcL = tabs;
  const float* QlevL = tabs + 96;
  const float* QwL = tabs + 672;
  const float* RtabL = tabs + 768;

  const int tb = base + 20 * t;
  float4 acc[5];
#pragma unroll
  for (int i = 0; i < 5; ++i) acc[i] = make_float4(0.f, 0.f, 0.f, 0.f);

  for (int g = 0; g < 3; ++g) {
    float A1[8], A2[8], B0[8], GN[8];
#pragma unroll
    for (int j = 0; j < 8; ++j) {
      int k = g * 8 + j;
      float4 bc = *(const float4*)&bandcL[k * 4];
      A1[j] = bc.x; A2[j] = bc.y; B0[j] = bc.z;
      GN[j] = gains[k];
    }
    float cv0[8], cv1[8];
#pragma unroll
    for (int j = 0; j < 8; ++j) cv0[j] = cv1[j] = 0.f;
    for (int i = 0; i < 5; ++i) {
      int n = tb + 4 * i;
      float4 xv = make_float4(0.f, 0.f, 0.f, 0.f);
      if (n >= 0) xv = *(const float4*)&sl[n - s2];
#pragma unroll
      for (int e = 0; e < 4; ++e) {
        float xi = e == 0 ? xv.x : e == 1 ? xv.y : e == 2 ? xv.z : xv.w;
#pragma unroll
        for (int j = 0; j < 8; ++j) {
          float nc = fmaf(B0[j], xi, -fmaf(A1[j], cv0[j], A2[j] * cv1[j]));
          cv1[j] = cv0[j];
          cv0[j] = nc;
        }
      }
    }
    int kl = 0;
    for (int off = 1; off <= 32; off <<= 1, ++kl) {
      float q00[8], q01[8], q10[8], q11[8];
#pragma unroll
      for (int j = 0; j < 8; ++j) {
        float4 qv = *(const float4*)&QlevL[(kl * 24 + g * 8 + j) * 4];
        q00[j] = qv.x; q01[j] = qv.y; q10[j] = qv.z; q11[j] = qv.w;
      }
#pragma unroll
      for (int j = 0; j < 8; ++j) {
        float u0 = __shfl_up(cv0[j], off);
        float u1 = __shfl_up(cv1[j], off);
        if (lane >= off) {
          float nc0 = fmaf(q00[j], u0, fmaf(q01[j], u1, cv0[j]));
          float nc1 = fmaf(q10[j], u0, fmaf(q11[j], u1, cv1[j]));
          cv0[j] = nc0;
          cv1[j] = nc1;
        }
      }
    }
    __syncthreads();
    if (lane == 63) {
#pragma unroll
      for (int j = 0; j < 8; ++j) {
        lc0[wid][j] = cv0[j];
        lc1[wid][j] = cv1[j];
      }
    }
    __syncthreads();
    float qw00[8], qw01[8], qw10[8], qw11[8];
#pragma unroll
    for (int j = 0; j < 8; ++j) {
      float4 qv = *(const float4*)&QwL[(g * 8 + j) * 4];
      qw00[j] = qv.x; qw01[j] = qv.y; qw10[j] = qv.z; qw11[j] = qv.w;
    }
    float car0[8], car1[8];
#pragma unroll
    for (int j = 0; j < 8; ++j) car0[j] = car1[j] = 0.f;
    for (int v = 0; v < wid; ++v) {
#pragma unroll
      for (int j = 0; j < 8; ++j) {
        float n0c = fmaf(qw00[j], car0[j], fmaf(qw01[j], car1[j], lc0[v][j]));
        float n1c = fmaf(qw10[j], car0[j], fmaf(qw11[j], car1[j], lc1[v][j]));
        car0[j] = n0c;
        car1[j] = n1c;
      }
    }
    float y1[8], y2[8];
#pragma unroll
    for (int j = 0; j < 8; ++j) {
      float4 rv = *(const float4*)&RtabL[((g * 8 + j) * 64 + lane) * 4];
      float e0 = __shfl_up(cv0[j], 1);
      float e1 = __shfl_up(cv1[j], 1);
      if (lane == 0) { e0 = 0.f; e1 = 0.f; }
      y1[j] = fmaf(rv.x, car0[j], fmaf(rv.y, car1[j], e0));
      y2[j] = fmaf(rv.z, car0[j], fmaf(rv.w, car1[j], e1));
    }
    if (tb + 20 > n0) {
      for (int i = 0; i < 5; ++i) {
        float4 xv = *(const float4*)&sl[tb - s2 + 4 * i];
        float4 ov = acc[i];
#pragma unroll
        for (int e = 0; e < 4; ++e) {
          float xi = e == 0 ? xv.x : e == 1 ? xv.y : e == 2 ? xv.z : xv.w;
          float a = 0.f;
#pragma unroll
          for (int j = 0; j < 8; ++j) {
            float yv = fmaf(B0[j], xi, -fmaf(A1[j], y1[j], A2[j] * y2[j]));
            y2[j] = y1[j];
            y1[j] = yv;
            a = fmaf(GN[j], yv, a);
          }
          if (e == 0) ov.x += a;
          else if (e == 1) ov.y += a;
          else if (e == 2) ov.z += a;
          else ov.w += a;
        }
        acc[i] = ov;
      }
    }
  }
  if (tb + 20 > n0) {
    float* outb = out + (size_t)b * NSAMP;
#pragma unroll
    for (int i = 0; i < 5; ++i) {
      int n = tb + 4 * i;
      if (n >= n0) *(float4*)&outb[n] = acc[i];
    }
  }
}

// ======== single kernel, 256 blocks; dynamic LDS 162880 B ========
__global__ void __launch_bounds__(256, 1) synth_all(
    const float* __restrict__ exc, const float* __restrict__ pitch,
    const float* __restrict__ w1, const float* __restrict__ b1,
    const float* __restrict__ w2, const float* __restrict__ b2,
    const float* __restrict__ eg, const float* __restrict__ gains,
    float* __restrict__ buf1, int* __restrict__ flags,
    float* __restrict__ out) {
  extern __shared__ float smem[];
  const int blk = blockIdx.x;
  const int b = blk >> 5, q = blk & 31;
  const int t = threadIdx.x;

  BParams P = compute_params(b, pitch, w1, b1, w2, b2);
  if (blk == 0 && t < 64) {
    int bb = (t < 8) ? t : 0;
    BParams Q = compute_params(bb, pitch, w1, b1, w2, b2);
    float slc = 0.f, slm = 0.f, slp = 0.f;
    for (int i = 0; i < 8; ++i) {
      slc += rlv(Q.lc, i);
      slm += rlv(Q.lm, i);
      slp += rlv(Q.lp, i);
    }
    if (t == 0) {
      out[8 * NSAMP + 0] = slc / 8.0f;
      out[8 * NSAMP + 1] = slm / 8.0f;
      out[8 * NSAMP + 2] = slp / 8.0f;
    }
  }

  // ---- phase 1: KS slice q (writes buf1[n0, n0+1024)); tables generated ----
  ks_phase(b, q, P, exc, eg[0], buf1, smem, (int*)&smem[PROG_OFF],
           smem + TABS_OFF, t);
  __syncthreads();  // drain wave0's global stores + table writes

  // ---- handoff: publish own flag, wait for same-batch predecessors ----
  const int n0 = q << 10;
  int s2 = n0 - 4096 - 256;
  if (s2 < 0) s2 = 0;
  const int qlo = s2 >> 10;
  if (t == 0) {
    __hip_atomic_store(&flags[blk], FLAG_MAGIC, __ATOMIC_RELEASE,
                       __HIP_MEMORY_SCOPE_AGENT);
    for (int f = qlo; f < q; ++f) {
      while (__hip_atomic_load(&flags[b * 32 + f], __ATOMIC_ACQUIRE,
                               __HIP_MEMORY_SCOPE_AGENT) != FLAG_MAGIC) {
        __builtin_amdgcn_s_sleep(8);
      }
    }
  }
  __syncthreads();

  // ---- phase 2: body slice q (xall region reused; tables persist) ----
  body_phase(b, q, P, gains, buf1, out, smem, smem + 6144,
             (float(*)[8])(smem + 6152), (float(*)[8])(smem + 6184),
             smem + TABS_OFF, t);
}

extern "C" void kernel_launch(void* const* d_in, const int* in_sizes, int n_in,
                              void* d_out, int out_size, void* d_ws, size_t ws_size,
                              hipStream_t stream) {
  const float* exc = (const float*)d_in[0];
  const float* pitch = (const float*)d_in[1];
  const float* w1 = (const float*)d_in[2];
  const float* b1 = (const float*)d_in[3];
  const float* w2 = (const float*)d_in[4];
  const float* b2 = (const float*)d_in[5];
  const float* eg = (const float*)d_in[6];
  const float* bg = (const float*)d_in[7];
  float* out = (float*)d_out;
  float* buf1 = (float*)d_ws;             // 8*NSAMP floats (KS output)
  int* flags = (int*)(buf1 + 8 * NSAMP);  // 256 flags (poison != MAGIC)

  static int lds_set = 0;
  if (!lds_set) {
    hipFuncSetAttribute(reinterpret_cast<const void*>(synth_all),
                        hipFuncAttributeMaxDynamicSharedMemorySize,
                        SMEM_FLOATS * 4);
    lds_set = 1;
  }
  hipLaunchKernelGGL(synth_all, dim3(256), dim3(256), SMEM_FLOATS * 4, stream,
                     exc, pitch, w1, b1, w2, b2, eg, bg, buf1, flags, out);
}

// Round 9
// 109.081 us; speedup vs baseline: 1.0542x; 1.0542x over previous
//
#include <hip/hip_runtime.h>
#include <math.h>

#define NSAMP 32768
#define FS_F 44100.0f
#define PI_F 3.14159265358979323846f
#define T1 1024  // KS slice length (32 slices/batch)
#define FLAG_MAGIC 0x5A5A5A5A

// LDS layout (floats, dynamic):
//   xall [0, 33792)      whole-span preLP'd excitation (32768 + 1024 pad)
//   prog [33792]         scan progress counter (int, 16-float slot)
//   tabs [33808, 40720)  body tables (bandc/Qlev/Qw/Rtab)
// body overlays: sl = [0,5376), body lws/lc0/lc1 at [6144..6248)
#define XALL_FLOATS 33792
#define PROG_OFF 33792
#define TABS_OFF 33808
#define SMEM_FLOATS 40720  // 162880 bytes (<= 163840)

struct BParams {
  float alpha, alpha_p;
  float fr, g, s;
  int Di;
  float lc, lm, lp;
};

__device__ inline float sigmoidf_(float x) { return 1.0f / (1.0f + expf(-x)); }

__device__ inline BParams compute_params(int b, const float* __restrict__ pitch,
                                         const float* __restrict__ w1,
                                         const float* __restrict__ b1,
                                         const float* __restrict__ w2,
                                         const float* __restrict__ b2) {
  BParams P;
  float p = pitch[b];
  float h[16];
#pragma unroll
  for (int i = 0; i < 16; ++i) {
    float v = fmaf(p, w1[i], b1[i]);
    h[i] = v > 0.0f ? v : 0.0f;
  }
  float m[3];
#pragma unroll
  for (int j = 0; j < 3; ++j) {
    float acc = b2[j];
#pragma unroll
    for (int i = 0; i < 16; ++i) acc = fmaf(h[i], w2[j * 16 + i], acc);
    m[j] = acc;
  }
  P.lc = fminf(fmaxf(m[0], -2.0f), 2.5f);
  P.lm = fminf(fmaxf(m[1], -2.5f), 0.0f);
  P.lp = fminf(fmaxf(m[2], -4.0f), 4.0f);
  P.g = 0.999f * sigmoidf_(P.lc);
  P.s = sigmoidf_(P.lm);
  float f0 = fmaxf(p, 60.0f);
  float D = fminf(fmaxf(FS_F / f0, 2.0f), 735.0f);
  int Di = (int)floorf(D);
  P.fr = D - (float)Di;
  P.Di = Di;
  float mult = fminf(fmaxf(2.0f + 6.0f * (f0 - 60.0f) / 600.0f, 2.0f), 8.0f);
  float cutoff = fminf(2.0f * PI_F * f0 * mult / FS_F, PI_F * 0.9f);
  P.alpha = 1.0f - expf(-cutoff);
  float cpost = fminf(PI_F * sigmoidf_(P.lp), PI_F * 0.99f);
  P.alpha_p = 1.0f - expf(-cpost);
  return P;
}

// lane helpers (wave64)
__device__ inline float rlv(float v, int l) {
  return __int_as_float(__builtin_amdgcn_readlane(__float_as_int(v), l));
}
__device__ inline float shr1(float v, float bnd) {
  return __int_as_float(__builtin_amdgcn_update_dpp(
      __float_as_int(bnd), __float_as_int(v), 0x138 /*wave_shr:1*/, 0xf, 0xf,
      false));
}
// rotate right by 1: lane0 <- lane63
__device__ inline float ror1(float v) {
  return __int_as_float(__builtin_amdgcn_update_dpp(
      __float_as_int(v), __float_as_int(v), 0x13C /*wave_ror:1*/, 0xf, 0xf,
      false));
}
// DPP with compile-time control; invalid/masked-out lanes read 0
template <int CTRL>
__device__ inline float dppz(float v) {
  return __int_as_float(__builtin_amdgcn_update_dpp(
      0, __float_as_int(v), CTRL, 0xf, 0xf, true));
}
template <int CTRL, int RMASK>
__device__ inline float dppm(float v) {
  return __int_as_float(__builtin_amdgcn_update_dpp(
      0, __float_as_int(v), CTRL, RMASK, 0xf, false));
}

__device__ inline void band_coef(int k, float& a1, float& a2, float& b0) {
  float fc = 80.0f * exp2f((float)k * (6.64385618977472436f / 23.0f));
  float w = 2.0f * PI_F * fc / FS_F;
  float r = expf(-PI_F * fc / (10.0f * FS_F));
  a1 = -2.0f * r * cosf(w);
  a2 = r * r;
  b0 = 1.0f - r;
}

// ---- data-independent body tables (verified bit-exact vs in-body compute) --
__device__ inline void gen_tables(float* __restrict__ tabs, int W) {
  if (W >= 120) return;
  const int j = W / 5, sub = W % 5;
  float A1, A2, B0;
  band_coef(j, A1, A2, B0);
  if (sub == 0) *(float4*)&tabs[j * 4] = make_float4(A1, A2, B0, 0.f);
  float Q00 = -A1, Q01 = -A2, Q10 = 1.f, Q11 = 0.f;
#pragma unroll
  for (int sq = 0; sq < 2; ++sq) {
    float n00 = fmaf(Q00, Q00, Q01 * Q10);
    float n01 = fmaf(Q00, Q01, Q01 * Q11);
    float n10 = fmaf(Q10, Q00, Q11 * Q10);
    float n11 = fmaf(Q10, Q01, Q11 * Q11);
    Q00 = n00; Q01 = n01; Q10 = n10; Q11 = n11;
  }
  float K00 = Q00, K01 = Q01, K10 = Q10, K11 = Q11;
#pragma unroll
  for (int sq = 0; sq < 2; ++sq) {
    float n00 = fmaf(Q00, Q00, Q01 * Q10);
    float n01 = fmaf(Q00, Q01, Q01 * Q11);
    float n10 = fmaf(Q10, Q00, Q11 * Q10);
    float n11 = fmaf(Q10, Q01, Q11 * Q11);
    Q00 = n00; Q01 = n01; Q10 = n10; Q11 = n11;
  }
  float L00[7], L01[7], L10[7], L11[7];
  L00[0] = fmaf(Q00, K00, Q01 * K10);
  L01[0] = fmaf(Q00, K01, Q01 * K11);
  L10[0] = fmaf(Q10, K00, Q11 * K10);
  L11[0] = fmaf(Q10, K01, Q11 * K11);
#pragma unroll
  for (int k = 0; k < 6; ++k) {
    float s00 = fmaf(L00[k], L00[k], L01[k] * L10[k]);
    float s01 = fmaf(L00[k], L01[k], L01[k] * L11[k]);
    float s10 = fmaf(L10[k], L00[k], L11[k] * L10[k]);
    float s11 = fmaf(L10[k], L01[k], L11[k] * L11[k]);
    L00[k + 1] = s00; L01[k + 1] = s01; L10[k + 1] = s10; L11[k + 1] = s11;
  }
  if (sub == 0) {
#pragma unroll
    for (int k = 0; k < 6; ++k)
      *(float4*)&tabs[96 + (k * 24 + j) * 4] =
          make_float4(L00[k], L01[k], L10[k], L11[k]);
    *(float4*)&tabs[672 + j * 4] = make_float4(L00[6], L01[6], L10[6], L11[6]);
  }
  int l0 = sub * 13, l1 = l0 + 13;
  if (l1 > 64) l1 = 64;
  for (int l = l0; l < l1; ++l) {
    float R00 = 1.f, R01 = 0.f, R10 = 0.f, R11 = 1.f;
#pragma unroll
    for (int bit = 0; bit < 6; ++bit) {
      if ((l >> bit) & 1) {
        float n00 = fmaf(L00[bit], R00, L01[bit] * R10);
        float n01 = fmaf(L00[bit], R01, L01[bit] * R11);
        float n10 = fmaf(L10[bit], R00, L11[bit] * R10);
        float n11 = fmaf(L10[bit], R01, L11[bit] * R11);
        R00 = n00; R01 = n01; R10 = n10; R11 = n11;
      }
    }
    *(float4*)&tabs[768 + (j * 64 + l) * 4] = make_float4(R00, R01, R10, R11);
  }
}

// wave1: register prefetch of one segment (32 samples/lane), guarded
__device__ inline void w1_load(const float* __restrict__ xg, int s1, int seg,
                               int lane, float4* pf) {
  const int base = s1 + (seg << 11) + (lane << 5);
#pragma unroll
  for (int i = 0; i < 8; ++i) {
    const int g = base + 4 * i;
    float4 v = make_float4(0.f, 0.f, 0.f, 0.f);
    if (g >= 0 && g + 3 < NSAMP) v = *(const float4*)&xg[g];
    pf[i] = v;
  }
}

// One KS period step. FP op sequence identical to R2..R7 (bit-identical).
#define KS_STEP(STORES)                                                       \
  do {                                                                        \
    float b2v[KNUM], b3v[KNUM];                                               \
    b2v[0] = shr1(yp[0], p1);                                                 \
    _Pragma("unroll") for (int k = 1; k < KNUM; ++k)                          \
        b2v[k] = shr1(yp[k], ror1(yp[k - 1]));                                \
    b3v[0] = shr1(b2v[0], p2);                                                \
    _Pragma("unroll") for (int k = 1; k < KNUM; ++k)                          \
        b3v[k] = shr1(b2v[k], ror1(b2v[k - 1]));                              \
    float p1n = rlv(yp[KNUM - 1], lq1);                                       \
    float p2n = rlv(b2v[KNUM - 1], lq1);                                      \
    _Pragma("unroll") for (int k = 0; k < KNUM; ++k)                          \
        yp[k] =                                                               \
            fmaf(c0w, yp[k], fmaf(c2w, b3v[k], fmaf(c1w, b2v[k], xC[k])));    \
    p1 = p1n;                                                                 \
    p2 = p2n;                                                                 \
    if (STORES) {                                                             \
      _Pragma("unroll") for (int k = 0; k < KNUM; ++k) {                      \
        int i = lane + (k << 6);                                              \
        int n = s1 + rel + i;                                                 \
        bool okl = (k < KNUM - 1) || (lane <= lq1);                           \
        if (okl && n >= n0 && n < end) yg[n] = yp[k];                         \
      }                                                                       \
    }                                                                         \
    int r2 = rel + 2 * C;                                                     \
    if (r2 < span) {                                                          \
      const float* xp = &xall[r2 + lane];                                     \
      _Pragma("unroll") for (int k = 0; k < KNUM; ++k) {                      \
        xC[k] = xN[k];                                                        \
        xN[k] = xp[k << 6];                                                   \
      }                                                                       \
    } else {                                                                  \
      _Pragma("unroll") for (int k = 0; k < KNUM; ++k) xC[k] = xN[k];         \
    }                                                                         \
    rel += C;                                                                 \
  } while (0)

// ---- single-wave KS recurrence (wave 0): flat LDS input, no block barriers.
template <int KNUM>
__device__ void ks_wave0(float* __restrict__ yg, const float* xall,
                         int* __restrict__ prog, int lane, int C, float c0w,
                         float c1w, float c2w, int s1, int n0, int end,
                         int span, int NSG) {
  const int lq1 = (C - 1) - (KNUM - 1) * 64;
  const int W = n0 - s1;
  float yp[KNUM], xC[KNUM], xN[KNUM];
  float p1 = 0.f, p2 = 0.f;
  int rel = 0;
#pragma unroll
  for (int k = 0; k < KNUM; ++k) { yp[k] = 0.f; xC[k] = 0.f; xN[k] = 0.f; }
  for (int s = 0; s < NSG; ++s) {
    int need = s + 3;
    if (need > NSG) need = NSG;
    while (__hip_atomic_load(prog, __ATOMIC_ACQUIRE,
                             __HIP_MEMORY_SCOPE_WORKGROUP) < need) {
      __builtin_amdgcn_s_sleep(1);
    }
    if (s == 0) {
#pragma unroll
      for (int k = 0; k < KNUM; ++k) {
        int i = lane + (k << 6);
        xC[k] = xall[i];
        xN[k] = xall[C + i];
      }
    }
    int fence = (s + 1) << 11;
    if (fence > span) fence = span;
    while (rel + C <= W && rel < fence) KS_STEP(false);
    while (rel < fence) KS_STEP(true);
  }
}

// ---- KS phase: wave1 free-runs the preLP scan into flat xall (DPP-based
// wave scan, no ds_bpermute), publishing a progress flag per segment; wave0
// free-runs the KS recurrence, polling the flag. waves 2-3 generate tables.
__device__ inline void ks_phase(int b, int q, const BParams& P,
                                const float* __restrict__ exc, float scale0,
                                float* __restrict__ buf1, float* xall,
                                int* prog, float* tabs, int t) {
  const int C = P.Di;
  const int n0 = q << 10;
  float lg = -logf(P.g);
  int Wp = (int)ceilf(10.5f / fmaxf(lg, 1e-6f));
  if (Wp > 64) Wp = 64;
  if (Wp < 4) Wp = 4;
  int W = Wp * C;
  if (W > n0) W = n0;
  W = (W + 3) & ~3;
  const int s1 = n0 - W;
  const int span = W + T1;
  const int end = n0 + T1;
  const int NSG = (span + 2047) >> 11;  // segments covering span, <= 16
  float* yg = buf1 + (size_t)b * NSAMP;
  const float* xg = exc + (size_t)b * NSAMP;

  const float c = 1.0f - P.alpha;
  const float scale = scale0 * P.alpha;
  const int lane = t & 63, wid = t >> 6;

  // init: progress flag + zero the pad region [NSG*2048, +1024)
  if (t == 0) *prog = 0;
  *(float4*)&xall[(NSG << 11) + 4 * t] = make_float4(0.f, 0.f, 0.f, 0.f);
  __syncthreads();

  const float c0w = P.g * (1.0f - P.s) * (1.0f - P.fr);
  const float c1w = P.g * ((1.0f - P.s) * P.fr + P.s * (1.0f - P.fr));
  const float c2w = P.g * P.s * P.fr;

  if (wid == 0) {
    switch ((C + 63) >> 6) {
      case 2:  ks_wave0<2>(yg, xall, prog, lane, C, c0w, c1w, c2w, s1, n0, end, span, NSG); break;
      case 3:  ks_wave0<3>(yg, xall, prog, lane, C, c0w, c1w, c2w, s1, n0, end, span, NSG); break;
      case 4:  ks_wave0<4>(yg, xall, prog, lane, C, c0w, c1w, c2w, s1, n0, end, span, NSG); break;
      case 5:  ks_wave0<5>(yg, xall, prog, lane, C, c0w, c1w, c2w, s1, n0, end, span, NSG); break;
      case 6:  ks_wave0<6>(yg, xall, prog, lane, C, c0w, c1w, c2w, s1, n0, end, span, NSG); break;
      case 7:  ks_wave0<7>(yg, xall, prog, lane, C, c0w, c1w, c2w, s1, n0, end, span, NSG); break;
      case 8:  ks_wave0<8>(yg, xall, prog, lane, C, c0w, c1w, c2w, s1, n0, end, span, NSG); break;
      case 9:  ks_wave0<9>(yg, xall, prog, lane, C, c0w, c1w, c2w, s1, n0, end, span, NSG); break;
      case 10: ks_wave0<10>(yg, xall, prog, lane, C, c0w, c1w, c2w, s1, n0, end, span, NSG); break;
      case 11: ks_wave0<11>(yg, xall, prog, lane, C, c0w, c1w, c2w, s1, n0, end, span, NSG); break;
      default: ks_wave0<12>(yg, xall, prog, lane, C, c0w, c1w, c2w, s1, n0, end, span, NSG); break;
    }
  } else if (wid == 1) {
    // producer: scan segments -1 (vrun pre-warm, no write) .. NSG-1.
    // Serial-chain-minimized: 4x8 split S-reduce + DPP wave scan (row_shr
    // 1,2,4,8 then row_bcast:15/31 with per-lane multipliers).
    float c2v = c * c, c4 = c2v * c2v, c8 = c4 * c4;
    float m1 = c8, m2 = m1 * m1, m4 = m2 * m2, m8 = m4 * m4, m16 = m8 * m8,
          m32 = m16 * m16;
    float c512 = m32 * m32;
    float c1024 = c512 * c512;
    float c2048 = c1024 * c1024;
    const float n1 = m4, n2 = m8, n4 = m16, n8 = m32;  // c^32..c^256
    const float l2c = log2f(c);
    const float c32lane = exp2f((float)(lane << 5) * l2c);
    const int p15 = lane & 15;
    const float mulA = exp2f((float)(32 * (p15 + 1)) * l2c);
    const float mulB =
        exp2f((float)(32 * (p15 + 1 + (((lane >> 4) == 3) ? 16 : 0))) * l2c);
    float vrun = 0.0f;
    float4 pf[8], pg[8];
    w1_load(xg, s1, -1, lane, pf);
    w1_load(xg, s1, 0, lane, pg);
    for (int ls = -1; ls < NSG; ++ls) {
      // S-reduce: 4 independent chains of 8, then merge
      float Sa = 0.f, Sb = 0.f, Sc = 0.f, Sd = 0.f;
      Sa = fmaf(c, Sa, scale * pf[0].x); Sa = fmaf(c, Sa, scale * pf[0].y);
      Sa = fmaf(c, Sa, scale * pf[0].z); Sa = fmaf(c, Sa, scale * pf[0].w);
      Sa = fmaf(c, Sa, scale * pf[1].x); Sa = fmaf(c, Sa, scale * pf[1].y);
      Sa = fmaf(c, Sa, scale * pf[1].z); Sa = fmaf(c, Sa, scale * pf[1].w);
      Sb = fmaf(c, Sb, scale * pf[2].x); Sb = fmaf(c, Sb, scale * pf[2].y);
      Sb = fmaf(c, Sb, scale * pf[2].z); Sb = fmaf(c, Sb, scale * pf[2].w);
      Sb = fmaf(c, Sb, scale * pf[3].x); Sb = fmaf(c, Sb, scale * pf[3].y);
      Sb = fmaf(c, Sb, scale * pf[3].z); Sb = fmaf(c, Sb, scale * pf[3].w);
      Sc = fmaf(c, Sc, scale * pf[4].x); Sc = fmaf(c, Sc, scale * pf[4].y);
      Sc = fmaf(c, Sc, scale * pf[4].z); Sc = fmaf(c, Sc, scale * pf[4].w);
      Sc = fmaf(c, Sc, scale * pf[5].x); Sc = fmaf(c, Sc, scale * pf[5].y);
      Sc = fmaf(c, Sc, scale * pf[5].z); Sc = fmaf(c, Sc, scale * pf[5].w);
      Sd = fmaf(c, Sd, scale * pf[6].x); Sd = fmaf(c, Sd, scale * pf[6].y);
      Sd = fmaf(c, Sd, scale * pf[6].z); Sd = fmaf(c, Sd, scale * pf[6].w);
      Sd = fmaf(c, Sd, scale * pf[7].x); Sd = fmaf(c, Sd, scale * pf[7].y);
      Sd = fmaf(c, Sd, scale * pf[7].z); Sd = fmaf(c, Sd, scale * pf[7].w);
      float S = fmaf(c8, fmaf(c8, fmaf(c8, Sa, Sb), Sc), Sd);
      // DPP geometric prefix scan across 64 lanes (factor c^32 per lane)
      float Sw = S, u;
      u = dppz<0x111>(Sw); Sw = fmaf(n1, u, Sw);         // row_shr:1
      u = dppz<0x112>(Sw); Sw = fmaf(n2, u, Sw);         // row_shr:2
      u = dppz<0x114>(Sw); Sw = fmaf(n4, u, Sw);         // row_shr:4
      u = dppz<0x118>(Sw); Sw = fmaf(n8, u, Sw);         // row_shr:8
      u = dppm<0x142, 0xa>(Sw); Sw = fmaf(mulA, u, Sw);  // bcast15 rows 1,3
      u = dppm<0x143, 0xc>(Sw); Sw = fmaf(mulB, u, Sw);  // bcast31 rows 2,3
      float tot = rlv(Sw, 63);
      float Sex = dppz<0x138>(Sw);  // exclusive: wave_shr:1, lane0 -> 0
      if (ls >= 0) {
        float v = fmaf(c32lane, vrun, Sex);
        const int o = (ls << 11) + (lane << 5);
#pragma unroll
        for (int i = 0; i < 8; ++i) {
          float4 y;
          v = fmaf(c, v, scale * pf[i].x); y.x = v;
          v = fmaf(c, v, scale * pf[i].y); y.y = v;
          v = fmaf(c, v, scale * pf[i].z); y.z = v;
          v = fmaf(c, v, scale * pf[i].w); y.w = v;
          *(float4*)&xall[o + 4 * i] = y;
        }
      }
      vrun = fmaf(c2048, vrun, tot);
      if (ls >= 0 && lane == 0) {
        // release: drains the ds_writes above before publishing
        __hip_atomic_store(prog, ls + 1, __ATOMIC_RELEASE,
                           __HIP_MEMORY_SCOPE_WORKGROUP);
      }
#pragma unroll
      for (int i = 0; i < 8; ++i) pf[i] = pg[i];
      if (ls + 2 < NSG) w1_load(xg, s1, ls + 2, lane, pg);
    }
  } else {
    gen_tables(tabs, (wid - 2) * 64 + lane);
  }
}

// One-pole scan over [s2, s2+nt*2048) from global into LDS sl[n-s2], reads
// clamped at `lim`. DPP wave scan (factor c^8 per lane).
__device__ inline void lpc_lds(const float* __restrict__ xg,
                               float* __restrict__ sl, int s2, int nt, int lim,
                               float scale, float c, int t, float* lws) {
  const int lane = t & 63, wid = t >> 6;
  float c2v = c * c, c4 = c2v * c2v, c8 = c4 * c4;
  float m1 = c8, m2 = m1 * m1, m4 = m2 * m2, m8 = m4 * m4, m16 = m8 * m8,
        m32 = m16 * m16;
  float c512 = m32 * m32;
  float c2048 = c512 * c512;
  c2048 *= c2048;
  float l2c = log2f(c);
  float c8lane = exp2f((float)(8 * lane) * l2c);
  float cgk = exp2f((float)(8 * t) * l2c);
  const int p15 = lane & 15;
  const float mulA = exp2f((float)(8 * (p15 + 1)) * l2c);
  const float mulB =
      exp2f((float)(8 * (p15 + 1 + (((lane >> 4) == 3) ? 16 : 0))) * l2c);
  float vrun = 0.0f;
  for (int tile = 0; tile < nt; ++tile) {
    __syncthreads();
    int g0 = s2 + (tile << 11) + 8 * t;
    float4 xa = make_float4(0.f, 0.f, 0.f, 0.f);
    float4 xb = make_float4(0.f, 0.f, 0.f, 0.f);
    if (g0 + 3 < lim) xa = *(const float4*)&xg[g0];
    if (g0 + 7 < lim) xb = *(const float4*)&xg[g0 + 4];
    float S = 0.0f;
    S = fmaf(c, S, scale * xa.x); S = fmaf(c, S, scale * xa.y);
    S = fmaf(c, S, scale * xa.z); S = fmaf(c, S, scale * xa.w);
    S = fmaf(c, S, scale * xb.x); S = fmaf(c, S, scale * xb.y);
    S = fmaf(c, S, scale * xb.z); S = fmaf(c, S, scale * xb.w);
    float Sw = S, u;
    u = dppz<0x111>(Sw); Sw = fmaf(m1, u, Sw);
    u = dppz<0x112>(Sw); Sw = fmaf(m2, u, Sw);
    u = dppz<0x114>(Sw); Sw = fmaf(m4, u, Sw);
    u = dppz<0x118>(Sw); Sw = fmaf(m8, u, Sw);
    u = dppm<0x142, 0xa>(Sw); Sw = fmaf(mulA, u, Sw);
    u = dppm<0x143, 0xc>(Sw); Sw = fmaf(mulB, u, Sw);
    if (lane == 63) lws[wid] = Sw;
    __syncthreads();
    float a0 = lws[0], a1w = lws[1], a2w = lws[2], a3w = lws[3];
    float carry = (wid == 1)   ? a0
                  : (wid == 2) ? fmaf(c512, a0, a1w)
                  : (wid == 3) ? fmaf(c512, fmaf(c512, a0, a1w), a2w)
                               : 0.0f;
    float Sex = dppz<0x138>(Sw);  // exclusive shift, lane0 -> 0
    Sex = fmaf(c8lane, carry, Sex);
    float v = fmaf(cgk, vrun, Sex);
    int o = g0 - s2;
    float4 ya, yb;
    v = fmaf(c, v, scale * xa.x); ya.x = v;
    v = fmaf(c, v, scale * xa.y); ya.y = v;
    v = fmaf(c, v, scale * xa.z); ya.z = v;
    v = fmaf(c, v, scale * xa.w); ya.w = v;
    v = fmaf(c, v, scale * xb.x); yb.x = v;
    v = fmaf(c, v, scale * xb.y); yb.y = v;
    v = fmaf(c, v, scale * xb.z); yb.z = v;
    v = fmaf(c, v, scale * xb.w); yb.w = v;
    *(float4*)&sl[o] = ya;
    *(float4*)&sl[o + 4] = yb;
    float tS = fmaf(c512, fmaf(c512, fmaf(c512, a0, a1w), a2w), a3w);
    vrun = fmaf(c2048, vrun, tS);
  }
}

// ---- body phase, T2=1024; matrix powers loaded from LDS tables ----
__device__ inline void body_phase(int b, int q, const BParams& P,
                                  const float* __restrict__ gains,
                                  const float* __restrict__ buf1,
                                  float* __restrict__ out, float* sl,
                                  float* lws, float (*lc0)[8],
                                  float (*lc1)[8], const float* tabs, int t) {
  const int lane = t & 63, wid = t >> 6;
  const int n0 = q << 10;
  const int base = n0 - 4096;
  int s2 = base - 256;
  if (s2 < 0) s2 = 0;
  const int end = n0 + 1024;
  const int nt = (end - s2 + 2047) >> 11;  // <= 3

  lpc_lds(buf1 + (size_t)b * NSAMP, sl, s2, nt, end, P.alpha_p,
          1.0f - P.alpha_p, t, lws);
  __syncthreads();

  const float* bandcL = tabs;
  const float* QlevL = tabs + 96;
  const float* QwL = tabs + 672;
  const float* RtabL = tabs + 768;

  const int tb = base + 20 * t;
  float4 acc[5];
#pragma unroll
  for (int i = 0; i < 5; ++i) acc[i] = make_float4(0.f, 0.f, 0.f, 0.f);

  for (int g = 0; g < 3; ++g) {
    float A1[8], A2[8], B0[8], GN[8];
#pragma unroll
    for (int j = 0; j < 8; ++j) {
      int k = g * 8 + j;
      float4 bc = *(const float4*)&bandcL[k * 4];
      A1[j] = bc.x; A2[j] = bc.y; B0[j] = bc.z;
      GN[j] = gains[k];
    }
    float cv0[8], cv1[8];
#pragma unroll
    for (int j = 0; j < 8; ++j) cv0[j] = cv1[j] = 0.f;
    for (int i = 0; i < 5; ++i) {
      int n = tb + 4 * i;
      float4 xv = make_float4(0.f, 0.f, 0.f, 0.f);
      if (n >= 0) xv = *(const float4*)&sl[n - s2];
#pragma unroll
      for (int e = 0; e < 4; ++e) {
        float xi = e == 0 ? xv.x : e == 1 ? xv.y : e == 2 ? xv.z : xv.w;
#pragma unroll
        for (int j = 0; j < 8; ++j) {
          float nc = fmaf(B0[j], xi, -fmaf(A1[j], cv0[j], A2[j] * cv1[j]));
          cv1[j] = cv0[j];
          cv0[j] = nc;
        }
      }
    }
    int kl = 0;
    for (int off = 1; off <= 32; off <<= 1, ++kl) {
      float q00[8], q01[8], q10[8], q11[8];
#pragma unroll
      for (int j = 0; j < 8; ++j) {
        float4 qv = *(const float4*)&QlevL[(kl * 24 + g * 8 + j) * 4];
        q00[j] = qv.x; q01[j] = qv.y; q10[j] = qv.z; q11[j] = qv.w;
      }
#pragma unroll
      for (int j = 0; j < 8; ++j) {
        float u0 = __shfl_up(cv0[j], off);
        float u1 = __shfl_up(cv1[j], off);
        if (lane >= off) {
          float nc0 = fmaf(q00[j], u0, fmaf(q01[j], u1, cv0[j]));
          float nc1 = fmaf(q10[j], u0, fmaf(q11[j], u1, cv1[j]));
          cv0[j] = nc0;
          cv1[j] = nc1;
        }
      }
    }
    __syncthreads();
    if (lane == 63) {
#pragma unroll
      for (int j = 0; j < 8; ++j) {
        lc0[wid][j] = cv0[j];
        lc1[wid][j] = cv1[j];
      }
    }
    __syncthreads();
    float qw00[8], qw01[8], qw10[8], qw11[8];
#pragma unroll
    for (int j = 0; j < 8; ++j) {
      float4 qv = *(const float4*)&QwL[(g * 8 + j) * 4];
      qw00[j] = qv.x; qw01[j] = qv.y; qw10[j] = qv.z; qw11[j] = qv.w;
    }
    float car0[8], car1[8];
#pragma unroll
    for (int j = 0; j < 8; ++j) car0[j] = car1[j] = 0.f;
    for (int v = 0; v < wid; ++v) {
#pragma unroll
      for (int j = 0; j < 8; ++j) {
        float n0c = fmaf(qw00[j], car0[j], fmaf(qw01[j], car1[j], lc0[v][j]));
        float n1c = fmaf(qw10[j], car0[j], fmaf(qw11[j], car1[j], lc1[v][j]));
        car0[j] = n0c;
        car1[j] = n1c;
      }
    }
    float y1[8], y2[8];
#pragma unroll
    for (int j = 0; j < 8; ++j) {
      float4 rv = *(const float4*)&RtabL[((g * 8 + j) * 64 + lane) * 4];
      float e0 = dppz<0x138>(cv0[j]);  // exclusive shift, lane0 -> 0
      float e1 = dppz<0x138>(cv1[j]);
      y1[j] = fmaf(rv.x, car0[j], fmaf(rv.y, car1[j], e0));
      y2[j] = fmaf(rv.z, car0[j], fmaf(rv.w, car1[j], e1));
    }
    if (tb + 20 > n0) {
      for (int i = 0; i < 5; ++i) {
        float4 xv = *(const float4*)&sl[tb - s2 + 4 * i];
        float4 ov = acc[i];
#pragma unroll
        for (int e = 0; e < 4; ++e) {
          float xi = e == 0 ? xv.x : e == 1 ? xv.y : e == 2 ? xv.z : xv.w;
          float a = 0.f;
#pragma unroll
          for (int j = 0; j < 8; ++j) {
            float yv = fmaf(B0[j], xi, -fmaf(A1[j], y1[j], A2[j] * y2[j]));
            y2[j] = y1[j];
            y1[j] = yv;
            a = fmaf(GN[j], yv, a);
          }
          if (e == 0) ov.x += a;
          else if (e == 1) ov.y += a;
          else if (e == 2) ov.z += a;
          else ov.w += a;
        }
        acc[i] = ov;
      }
    }
  }
  if (tb + 20 > n0) {
    float* outb = out + (size_t)b * NSAMP;
#pragma unroll
    for (int i = 0; i < 5; ++i) {
      int n = tb + 4 * i;
      if (n >= n0) *(float4*)&outb[n] = acc[i];
    }
  }
}

// ======== single kernel, 256 blocks; dynamic LDS 162880 B ========
__global__ void __launch_bounds__(256, 1) synth_all(
    const float* __restrict__ exc, const float* __restrict__ pitch,
    const float* __restrict__ w1, const float* __restrict__ b1,
    const float* __restrict__ w2, const float* __restrict__ b2,
    const float* __restrict__ eg, const float* __restrict__ gains,
    float* __restrict__ buf1, int* __restrict__ flags,
    float* __restrict__ out) {
  extern __shared__ float smem[];
  const int blk = blockIdx.x;
  const int b = blk >> 5, q = blk & 31;
  const int t = threadIdx.x;

  BParams P = compute_params(b, pitch, w1, b1, w2, b2);
  if (blk == 0 && t < 64) {
    int bb = (t < 8) ? t : 0;
    BParams Q = compute_params(bb, pitch, w1, b1, w2, b2);
    float slc = 0.f, slm = 0.f, slp = 0.f;
    for (int i = 0; i < 8; ++i) {
      slc += rlv(Q.lc, i);
      slm += rlv(Q.lm, i);
      slp += rlv(Q.lp, i);
    }
    if (t == 0) {
      out[8 * NSAMP + 0] = slc / 8.0f;
      out[8 * NSAMP + 1] = slm / 8.0f;
      out[8 * NSAMP + 2] = slp / 8.0f;
    }
  }

  // ---- phase 1: KS slice q (writes buf1[n0, n0+1024)); tables generated ----
  ks_phase(b, q, P, exc, eg[0], buf1, smem, (int*)&smem[PROG_OFF],
           smem + TABS_OFF, t);
  __syncthreads();  // drain wave0's global stores + table writes

  // ---- handoff: publish own flag, wait for same-batch predecessors ----
  const int n0 = q << 10;
  int s2 = n0 - 4096 - 256;
  if (s2 < 0) s2 = 0;
  const int qlo = s2 >> 10;
  if (t == 0) {
    __hip_atomic_store(&flags[blk], FLAG_MAGIC, __ATOMIC_RELEASE,
                       __HIP_MEMORY_SCOPE_AGENT);
    for (int f = qlo; f < q; ++f) {
      while (__hip_atomic_load(&flags[b * 32 + f], __ATOMIC_ACQUIRE,
                               __HIP_MEMORY_SCOPE_AGENT) != FLAG_MAGIC) {
        __builtin_amdgcn_s_sleep(8);
      }
    }
  }
  __syncthreads();

  // ---- phase 2: body slice q (xall region reused; tables persist) ----
  body_phase(b, q, P, gains, buf1, out, smem, smem + 6144,
             (float(*)[8])(smem + 6152), (float(*)[8])(smem + 6184),
             smem + TABS_OFF, t);
}

extern "C" void kernel_launch(void* const* d_in, const int* in_sizes, int n_in,
                              void* d_out, int out_size, void* d_ws, size_t ws_size,
                              hipStream_t stream) {
  const float* exc = (const float*)d_in[0];
  const float* pitch = (const float*)d_in[1];
  const float* w1 = (const float*)d_in[2];
  const float* b1 = (const float*)d_in[3];
  const float* w2 = (const float*)d_in[4];
  const float* b2 = (const float*)d_in[5];
  const float* eg = (const float*)d_in[6];
  const float* bg = (const float*)d_in[7];
  float* out = (float*)d_out;
  float* buf1 = (float*)d_ws;             // 8*NSAMP floats (KS output)
  int* flags = (int*)(buf1 + 8 * NSAMP);  // 256 flags (poison != MAGIC)

  static int lds_set = 0;
  if (!lds_set) {
    (void)hipFuncSetAttribute(reinterpret_cast<const void*>(synth_all),
                              hipFuncAttributeMaxDynamicSharedMemorySize,
                              SMEM_FLOATS * 4);
    lds_set = 1;
  }
  hipLaunchKernelGGL(synth_all, dim3(256), dim3(256), SMEM_FLOATS * 4, stream,
                     exc, pitch, w1, b1, w2, b2, eg, bg, buf1, flags, out);
}